// Round 12
// baseline (167.328 us; speedup 1.0000x reference)
//
#include <hip/hip_runtime.h>
#include <hip/hip_bf16.h>
#include <math.h>

#define BB 32
#define NN 512

typedef _Float16 f16x8 __attribute__((ext_vector_type(8)));
typedef __fp16  fp16x2 __attribute__((ext_vector_type(2)));
typedef float f32x4 __attribute__((ext_vector_type(4)));

#define MFMA16(a, b, c) __builtin_amdgcn_mfma_f32_16x16x32_f16(a, b, c, 0, 0, 0)

union AF { f16x8 v; unsigned int u[4]; };

// monotone order-preserving float<->uint for atomicMax-based max reduction
static __device__ __forceinline__ unsigned int fenc(float x) {
    unsigned int u = __float_as_uint(x);
    return (u & 0x80000000u) ? ~u : (u | 0x80000000u);
}
static __device__ __forceinline__ float fdec(unsigned int k) {
    unsigned int u = (k & 0x80000000u) ? (k ^ 0x80000000u) : ~k;
    return __uint_as_float(u);
}

// ============ W^T fp16 prep (W0 + W1), XOR-swizzled granules + maxd init ====
__global__ __launch_bounds__(256) void k_wt_prep(
    const float* __restrict__ W0, _Float16* __restrict__ W0T,
    const float* __restrict__ W1, _Float16* __restrict__ W1T,
    unsigned int* __restrict__ maxdK)          // 512 keys (maxd0 | maxd1)
{
    int id = blockIdx.x * 256 + threadIdx.x;   // 0..4607
    if (id < 512) maxdK[id] = 0u;              // -inf key
    const float* W; _Float16* WT; int KT, task;
    if (id < 512) { W = W0; WT = W0T; KT = 64;  task = id; }
    else          { W = W1; WT = W1T; KT = 512; task = id - 512; }
    int n = task & 63, gabs = task >> 6;
    int c = gabs >> 3, g = gabs & 7;
    f16x8 hv;
#pragma unroll
    for (int e = 0; e < 8; ++e)
        hv[e] = (_Float16)W[(size_t)(gabs * 8 + e) * 64 + n];
    *(f16x8*)(WT + (size_t)n * KT + c * 64 + (g ^ (n & 7)) * 8) = hv;
}

// ============ shared epilogue: ctile -> s, dTg (+atomic max), fp16 hpT ======
static __device__ __forceinline__ void epi_sd_hpt(
    const float* ctile, const float* asd_f, int row0, int t,
    float* __restrict__ s, float* __restrict__ dTg, _Float16* __restrict__ hpT,
    unsigned int* __restrict__ maxdK)
{
    int b = row0 >> 9, jb = row0 & 511;
    if (t < 128) {
        int rr = t >> 3, h = t & 7;
        float sv = 0.f, dv = 0.f;
#pragma unroll
        for (int f = 0; f < 64; ++f) {
            float hv = ctile[rr * 66 + f];
            sv = fmaf(hv, asd_f[f * 8 + h], sv);
            dv = fmaf(hv, asd_f[512 + f * 8 + h], dv);
        }
        s[((size_t)b * NN + jb + rr) * 8 + h] = sv;
        dTg[((size_t)b * 8 + h) * NN + jb + rr] = dv;
        // wave-level max over the 16 rows of this tile (lanes sharing h)
        float m = dv;
        m = fmaxf(m, __shfl_xor(m, 8));
        m = fmaxf(m, __shfl_xor(m, 16));
        m = fmaxf(m, __shfl_xor(m, 32));
        if ((t & 63) < 8) atomicMax(maxdK + b * 8 + h, fenc(m));
    } else {
        int t2 = t - 128;
        int f = t2 >> 1, jl = (t2 & 1) * 8;
        f16x8 hv;
#pragma unroll
        for (int e = 0; e < 8; ++e)
            hv[e] = (_Float16)ctile[(jl + e) * 66 + f];
        *(f16x8*)(hpT + ((size_t)b * 64 + f) * NN + jb + jl) = hv;
    }
}

// ============ Layer-0 GEMM: fp16 MFMA, 16 rows/block, K=64 ==================
__global__ __launch_bounds__(256) void k_gemm0(
    const float* __restrict__ x, const _Float16* __restrict__ W0T,
    const float* __restrict__ a_src, const float* __restrict__ a_dst,
    float* __restrict__ s, float* __restrict__ dTg, _Float16* __restrict__ hpT,
    unsigned int* __restrict__ maxdK)
{
    __shared__ float ctile[16 * 66];
    __shared__ float asd_f[1024];
    int t = threadIdx.x, row0 = blockIdx.x * 16;
    int lane = t & 63, w = t >> 6, cn = lane & 15, rq = lane >> 4;

    ((float4*)asd_f)[t] = (t < 128) ? ((const float4*)a_src)[t]
                                    : ((const float4*)a_dst)[t - 128];
    f32x4 acc;
#pragma unroll
    for (int e = 0; e < 4; ++e) acc[e] = 0.f;
#pragma unroll
    for (int ks = 0; ks < 2; ++ks) {
        const float* xp = x + (size_t)(row0 + cn) * 64 + ks * 32 + rq * 8;
        float4 x0 = *(const float4*)xp, x1 = *(const float4*)(xp + 4);
        f16x8 ah = {(_Float16)x0.x, (_Float16)x0.y, (_Float16)x0.z, (_Float16)x0.w,
                    (_Float16)x1.x, (_Float16)x1.y, (_Float16)x1.z, (_Float16)x1.w};
        int nn = w * 16 + cn;
        f16x8 bh = *(const f16x8*)(W0T + (size_t)nn * 64 + (((ks * 4 + rq) ^ (nn & 7)) * 8));
        acc = MFMA16(ah, bh, acc);
    }
#pragma unroll
    for (int r = 0; r < 4; ++r)
        ctile[(rq * 4 + r) * 66 + w * 16 + cn] = acc[r];
    __syncthreads();
    epi_sd_hpt(ctile, asd_f, row0, t, s, dTg, hpT, maxdK);
}

// ============ fused attention v6: hT dbuf, 1 barrier/chunk, deep prefetch ===
// MODE 0: + gemm1 vs register-prefetched W1T ping/pong, epilogue s1/dTg1/hp1T
//         with fused atomic maxd1. MODE 1: head-mean fp32 out.
template<int MODE>
__global__ __launch_bounds__(256, 4) void k_attn_fused(
    const float* __restrict__ adj, const float* __restrict__ s,
    const float* __restrict__ dTg, const unsigned int* __restrict__ maxdK,
    const _Float16* __restrict__ hpT,
    const _Float16* __restrict__ W1T,
    const float* __restrict__ a_src, const float* __restrict__ a_dst,
    float* __restrict__ s_out, float* __restrict__ dTg_out,
    _Float16* __restrict__ hpT_out, unsigned int* __restrict__ maxdK_out,
    float* __restrict__ o_f)
{
    __shared__ __align__(16) char smem[32768];

    int blk = blockIdx.x;
    int vb = ((blk & 7) << 7) | (blk >> 3);    // XCD swizzle: 4 batches/XCD
    int b = vb >> 5, i0 = (vb & 31) << 4;
    int row0 = vb * 16;                        // = b*512 + i0
    int t = threadIdx.x, lane = t & 63, w = t >> 6;
    int cn = lane & 15, rq = lane >> 4;
    int h0 = 2 * w, h1 = h0 + 1;
    int myrow = i0 + cn;

    float sv0 = s[((size_t)b * NN + myrow) * 8 + h0];
    float sv1 = s[((size_t)b * NN + myrow) * 8 + h1];
    float M0 = fmaxf(sv0 + fdec(maxdK[b * 8 + h0]), 0.f);
    float M1 = fmaxf(sv1 + fdec(maxdK[b * 8 + h1]), 0.f);

    const float* arow = adj + ((size_t)b * NN + myrow) * NN;
    const float* dg0 = dTg + ((size_t)b * 8 + h0) * NN;
    const float* dg1 = dTg + ((size_t)b * 8 + h1) * NN;
    const _Float16* hb = hpT + (size_t)b * 64 * NN;

    // staging geometry: thread covers rows f0 and f0+32, granule g0
    int f0 = t >> 3, g0 = t & 7;
    int f1 = f0 + 32;                          // (f1&7)==(f0&7)
    int sw = ((g0 ^ (f0 & 7)) * 8);
    int sw0 = f0 * 64 + sw, sw1 = f1 * 64 + sw;

    f16x8 ones;
#pragma unroll
    for (int e = 0; e < 8; ++e) ones[e] = (_Float16)1.0f;

    f32x4 acc[2][4], accrs[2];
#pragma unroll
    for (int hh = 0; hh < 2; ++hh) {
#pragma unroll
        for (int e = 0; e < 4; ++e) accrs[hh][e] = 0.f;
#pragma unroll
        for (int ft = 0; ft < 4; ++ft)
#pragma unroll
            for (int e = 0; e < 4; ++e) acc[hh][ft][e] = 0.f;
    }

    // ---- prologue: chunk 0 hT + adj/d; commit to buffer 0; prefetch chunk 1
    uint4 rH0 = *(const uint4*)(hb + (size_t)f0 * 512 + g0 * 8);
    uint4 rH1 = *(const uint4*)(hb + (size_t)f1 * 512 + g0 * 8);
    float aa[2][8], dd0[2][8], dd1[2][8];
#pragma unroll
    for (int ks = 0; ks < 2; ++ks) {
        int j0 = ks * 32 + rq * 8;
        *(float4*)&aa[ks][0]  = *(const float4*)(arow + j0);
        *(float4*)&aa[ks][4]  = *(const float4*)(arow + j0 + 4);
        *(float4*)&dd0[ks][0] = *(const float4*)(dg0 + j0);
        *(float4*)&dd0[ks][4] = *(const float4*)(dg0 + j0 + 4);
        *(float4*)&dd1[ks][0] = *(const float4*)(dg1 + j0);
        *(float4*)&dd1[ks][4] = *(const float4*)(dg1 + j0 + 4);
    }
    {
        _Float16* hT0 = (_Float16*)smem;
        *(uint4*)&hT0[sw0] = rH0;
        *(uint4*)&hT0[sw1] = rH1;
    }
    __syncthreads();
    rH0 = *(const uint4*)(hb + (size_t)f0 * 512 + 64 + g0 * 8);
    rH1 = *(const uint4*)(hb + (size_t)f1 * 512 + 64 + g0 * 8);

    for (int jcx = 0; jcx < 8; ++jcx) {
        int jc = jcx * 64;
        _Float16* hTc = (_Float16*)(smem + (jcx & 1) * 8192);
        _Float16* hTn = (_Float16*)(smem + ((jcx & 1) ^ 1) * 8192);

        // ---- P-build both ks (consumes aa/dd of THIS chunk)
        AF aA[2], aB[2];
#pragma unroll
        for (int ks = 0; ks < 2; ++ks) {
            int j0 = jc + ks * 32 + rq * 8;
            int rel = myrow - j0;              // self-loop at e == rel
#pragma unroll
            for (int e = 0; e < 8; e += 2) {
                float pA[2], pB[2];
#pragma unroll
                for (int q = 0; q < 2; ++q) {
                    int ee = e + q;
                    bool con = (aa[ks][ee] != 0.f) || (ee == rel);
                    float e0 = sv0 + dd0[ks][ee];
                    float l0 = fmaxf(e0, 0.2f * e0);
                    float p0 = __expf(l0 - M0);
                    pA[q] = (con && l0 != 0.f) ? p0 : 0.f;   // mask + ==0 quirk
                    float e1 = sv1 + dd1[ks][ee];
                    float l1 = fmaxf(e1, 0.2f * e1);
                    float p1 = __expf(l1 - M1);
                    pB[q] = (con && l1 != 0.f) ? p1 : 0.f;
                }
                fp16x2 ka = __builtin_amdgcn_cvt_pkrtz(pA[0], pA[1]);
                fp16x2 kb = __builtin_amdgcn_cvt_pkrtz(pB[0], pB[1]);
                aA[ks].u[e >> 1] = __builtin_bit_cast(unsigned int, ka);
                aB[ks].u[e >> 1] = __builtin_bit_cast(unsigned int, kb);
            }
        }
        // ---- prefetch adj/d for NEXT chunk (regs now free)
        if (jcx < 7) {
#pragma unroll
            for (int ks = 0; ks < 2; ++ks) {
                int j0 = jc + 64 + ks * 32 + rq * 8;
                *(float4*)&aa[ks][0]  = *(const float4*)(arow + j0);
                *(float4*)&aa[ks][4]  = *(const float4*)(arow + j0 + 4);
                *(float4*)&dd0[ks][0] = *(const float4*)(dg0 + j0);
                *(float4*)&dd0[ks][4] = *(const float4*)(dg0 + j0 + 4);
                *(float4*)&dd1[ks][0] = *(const float4*)(dg1 + j0);
                *(float4*)&dd1[ks][4] = *(const float4*)(dg1 + j0 + 4);
            }
        }
        // ---- MFMA on current buffer
#pragma unroll
        for (int ks = 0; ks < 2; ++ks) {
            accrs[0] = MFMA16(aA[ks].v, ones, accrs[0]);
            accrs[1] = MFMA16(aB[ks].v, ones, accrs[1]);
#pragma unroll
            for (int ft = 0; ft < 4; ++ft) {
                int f = ft * 16 + cn;
                f16x8 bh = *(const f16x8*)&hTc[f * 64 + (((ks * 4 + rq) ^ (f & 7)) * 8)];
                acc[0][ft] = MFMA16(aA[ks].v, bh, acc[0][ft]);
                acc[1][ft] = MFMA16(aB[ks].v, bh, acc[1][ft]);
            }
        }
        // ---- commit next chunk's hT; issue chunk+2 loads
        if (jcx < 7) {
            *(uint4*)&hTn[sw0] = rH0;
            *(uint4*)&hTn[sw1] = rH1;
            if (jcx < 6) {
                rH0 = *(const uint4*)(hb + (size_t)f0 * 512 + jc + 128 + g0 * 8);
                rH1 = *(const uint4*)(hb + (size_t)f1 * 512 + jc + 128 + g0 * 8);
            }
        }
        __syncthreads();
    }

    float invr[2][4];
#pragma unroll
    for (int hh = 0; hh < 2; ++hh)
#pragma unroll
        for (int r = 0; r < 4; ++r) invr[hh][r] = 1.0f / accrs[hh][r];

    if (MODE == 0) {
        // ---- x1 tiles (normalized + ELU) into LDS, A-layout, XOR-swizzled
        _Float16* x1all = (_Float16*)smem;             // [8 heads][16*64], 16KB
#pragma unroll
        for (int hh = 0; hh < 2; ++hh) {
            int h = h0 + hh;
#pragma unroll
            for (int ft = 0; ft < 4; ++ft)
#pragma unroll
                for (int r = 0; r < 4; ++r) {
                    int il = rq * 4 + r;
                    float v = acc[hh][ft][r] * invr[hh][r];
                    v = v > 0.f ? v : __expf(v) - 1.f;   // ELU
                    int f = ft * 16 + cn;
                    x1all[h * 1024 + il * 64 + (((f >> 3) ^ (il & 7)) * 8) + (f & 7)] =
                        (_Float16)v;
                }
        }

        // ---- gemm1: A from LDS x1all, B = W1T ping/pong, register-prefetched
        _Float16* Bst[2] = { (_Float16*)(smem + 16384), (_Float16*)(smem + 24576) };
        {   // stage kc=0 (straight physical copy; global already swizzled)
#pragma unroll
            for (int u = 0; u < 2; ++u) {
                int idx = t + u * 256;
                *(uint4*)&Bst[0][idx * 8] =
                    *(const uint4*)(W1T + (size_t)(idx >> 3) * 512 + (idx & 7) * 8);
            }
        }
        f32x4 g1;
#pragma unroll
        for (int e = 0; e < 4; ++e) g1[e] = 0.f;
        uint4 rB0, rB1;
        for (int kc = 0; kc < 8; ++kc) {
            int cur = kc & 1;
            if (kc < 7) {   // issue next chunk's loads before the barrier
                rB0 = *(const uint4*)(W1T + (size_t)(t >> 3) * 512 + (kc + 1) * 64 + (t & 7) * 8);
                rB1 = *(const uint4*)(W1T + (size_t)((t + 256) >> 3) * 512 + (kc + 1) * 64 + (t & 7) * 8);
            }
            __syncthreads();   // Bst[cur] (committed prev iter) + x1all visible
#pragma unroll
            for (int ks = 0; ks < 2; ++ks) {
                int pa = (((ks * 4 + rq) ^ (cn & 7)) * 8);
                f16x8 ah = *(const f16x8*)&x1all[kc * 1024 + cn * 64 + pa];
                int nn = w * 16 + cn;
                f16x8 bh = *(const f16x8*)&Bst[cur][nn * 64 + (((ks * 4 + rq) ^ (nn & 7)) * 8)];
                g1 = MFMA16(ah, bh, g1);
            }
            if (kc < 7) {   // commit into the idle buffer
                *(uint4*)&Bst[cur ^ 1][t * 8] = rB0;
                *(uint4*)&Bst[cur ^ 1][(t + 256) * 8] = rB1;
            }
        }
        __syncthreads();                       // x1all dead -> reuse region
        float* ctile = (float*)smem;           // 4224 B
        float* asd_f = (float*)(smem + 4352);  // 4096 B
#pragma unroll
        for (int r = 0; r < 4; ++r)
            ctile[(rq * 4 + r) * 66 + w * 16 + cn] = g1[r];
        ((float4*)asd_f)[t] = (t < 128) ? ((const float4*)a_src)[t]
                                        : ((const float4*)a_dst)[t - 128];
        __syncthreads();
        epi_sd_hpt(ctile, asd_f, row0, t, s_out, dTg_out, hpT_out, maxdK_out);
    } else {
        float* red = (float*)smem;             // [4][16][64] fp32 = 16 KB
#pragma unroll
        for (int ft = 0; ft < 4; ++ft)
#pragma unroll
            for (int r = 0; r < 4; ++r) {
                int il = rq * 4 + r;
                float v = acc[0][ft][r] * invr[0][r]
                        + acc[1][ft][r] * invr[1][r];
                red[(w * 16 + il) * 64 + ft * 16 + cn] = v;
            }
        __syncthreads();
#pragma unroll
        for (int u = 0; u < 4; ++u) {
            int idx = t + u * 256;
            int il = idx >> 6, f = idx & 63;
            float sum = red[il * 64 + f] + red[(16 + il) * 64 + f]
                      + red[(32 + il) * 64 + f] + red[(48 + il) * 64 + f];
            o_f[((size_t)b * NN + i0 + il) * 64 + f] = sum * 0.125f;
        }
    }
}

extern "C" void kernel_launch(void* const* d_in, const int* in_sizes, int n_in,
                              void* d_out, int out_size, void* d_ws, size_t ws_size,
                              hipStream_t stream) {
    const float* x      = (const float*)d_in[0];
    const float* adj    = (const float*)d_in[1];
    const float* W0     = (const float*)d_in[4];
    const float* a_src0 = (const float*)d_in[5];
    const float* a_dst0 = (const float*)d_in[6];
    const float* W1     = (const float*)d_in[7];
    const float* a_src1 = (const float*)d_in[8];
    const float* a_dst1 = (const float*)d_in[9];
    float* out = (float*)d_out;

    float* ws = (float*)d_ws;
    const size_t R = (size_t)BB * NN;            // 16384 rows
    float* s0    = ws;                           // R*8
    float* dTg0  = s0 + R * 8;                   // 32*8*512
    float* s1    = dTg0 + (size_t)BB * 8 * NN;
    float* dTg1  = s1 + R * 8;
    unsigned int* maxdK = (unsigned int*)(dTg1 + (size_t)BB * 8 * NN);  // 512
    unsigned int* maxd0K = maxdK;
    unsigned int* maxd1K = maxdK + 256;
    _Float16* hp0T = (_Float16*)(maxdK + 512);   // 32*64*512
    _Float16* hp1T = hp0T + (size_t)BB * 64 * NN;
    _Float16* W0T  = hp1T + (size_t)BB * 64 * NN;   // 64*64
    _Float16* W1T  = W0T + (size_t)64 * 64;         // 64*512

    k_wt_prep<<<18, 256, 0, stream>>>(W0, W0T, W1, W1T, maxdK);
    k_gemm0<<<1024, 256, 0, stream>>>(x, W0T, a_src0, a_dst0, s0, dTg0, hp0T, maxd0K);
    k_attn_fused<0><<<1024, 256, 0, stream>>>(adj, s0, dTg0, maxd0K, hp0T,
                                              W1T, a_src1, a_dst1,
                                              s1, dTg1, hp1T, maxd1K, nullptr);
    k_attn_fused<1><<<1024, 256, 0, stream>>>(adj, s1, dTg1, maxd1K, hp1T,
                                              nullptr, nullptr, nullptr,
                                              nullptr, nullptr, nullptr, nullptr, out);
}